// Round 11
// baseline (80.261 us; speedup 1.0000x reference)
//
#include <hip/hip_runtime.h>

// feats [B=8, C=256, H=128, W=256] f32; labels [8,128,256] int32 in [0,19)
// out: means [19][256] then norm_means [19]  (4883 floats)
#define NCLS 19
#define NCH  256
#define HW   (128 * 256)         // 32768, pow2
#define NPIX (8 * HW)            // 262144
#define P    64                  // pixels per tile (256-B global segments/channel)
#define THP  68                  // bf16 tile row stride: 136 B, 8B-aligned b64, <=2-way banks
#define SQP  65                  // sqpart row stride (32 rows x 64 px)
#define SUMS (NCLS * NCH)        // 4864
#define PN_NORM SUMS
#define PN_CNT  (SUMS + NCLS)
#define PSTRIDE 4928             // per-block partial stride (floats)
#define GRID  512
#define TILES (NPIX / (P * GRID))   // 8

typedef __bf16 bf16x4v __attribute__((ext_vector_type(4)));
typedef __bf16 bf16x8v __attribute__((ext_vector_type(8)));
typedef float  f32x16v __attribute__((ext_vector_type(16)));
typedef int    int4v   __attribute__((ext_vector_type(4)));

// LDS-only barrier (no vmcnt drain): prefetch loads stay in flight.
__device__ __forceinline__ void bar_lds() {
    asm volatile("s_waitcnt lgkmcnt(0)" ::: "memory");
    __builtin_amdgcn_sched_barrier(0);
    __builtin_amdgcn_s_barrier();
    __builtin_amdgcn_sched_barrier(0);
}

__global__ __launch_bounds__(512) void accum_kernel(
    const float* __restrict__ feats, const int* __restrict__ labels,
    float* __restrict__ partials)
{
    __shared__ __bf16 tileh[NCH * THP];   // 34.8 KB  [c][px] bf16
    __shared__ float  sqpart[32 * SQP];   // 8.3 KB   [cb][px] x^2 partial (8 ch each)
    __shared__ float  accf[SUMS];         // 19.5 KB  K-half merge [k][c]
    __shared__ float  accN[NCLS];
    __shared__ float  accC[NCLS];
    __shared__ int    lab_s[P];           // ~63 KB total -> 2 blocks/CU

    const int t = threadIdx.x;
    if (t < NCLS) { accN[t] = 0.f; accC[t] = 0.f; }
    for (int j = t; j < SUMS; j += 512) accf[j] = 0.f;

    // Stage mapping: thread covers 8 channel rows x 4 px (256-B wave segments).
    const int px4 = (t & 15) * 4, cbase = t >> 4;     // cbase 0..31
    // MFMA mapping: 8 waves = (K-half ks) x (channel group cg).
    const int w = t >> 6, l = t & 63, h = l >> 5, col = l & 31;
    const int cg = w & 3, ks = w >> 2;
    const int c0 = cg * 64 + col, c1 = c0 + 32;
    const __bf16 ONE = (__bf16)1.0f, ZER = (__bf16)0.0f;

    f32x16v d0 = {}, d1 = {};             // class x {c0, c1} accumulators
    float4 v4[8];                         // 32 VGPR staging (vs r9's 64)
    int labv = 0;

    // ---- prologue: load + stage tile 0 ----
    {
        const int p0 = blockIdx.x * P, b = p0 >> 15, hw0 = p0 & (HW - 1);
        const float* fb = feats + (size_t)b * NCH * HW + hw0;
        #pragma unroll
        for (int i = 0; i < 8; ++i)
            v4[i] = *reinterpret_cast<const float4*>(fb + (size_t)(cbase + 32 * i) * HW + px4);
        if (t < P) labv = labels[p0 + t];
    }
    {
        float s0 = 0.f, s1 = 0.f, s2 = 0.f, s3 = 0.f;
        #pragma unroll
        for (int i = 0; i < 8; ++i) {
            const int c = cbase + 32 * i;
            bf16x4v hv = { (__bf16)v4[i].x, (__bf16)v4[i].y, (__bf16)v4[i].z, (__bf16)v4[i].w };
            *reinterpret_cast<bf16x4v*>(&tileh[c * THP + px4]) = hv;
            s0 += v4[i].x * v4[i].x; s1 += v4[i].y * v4[i].y;
            s2 += v4[i].z * v4[i].z; s3 += v4[i].w * v4[i].w;
        }
        sqpart[cbase * SQP + px4    ] = s0; sqpart[cbase * SQP + px4 + 1] = s1;
        sqpart[cbase * SQP + px4 + 2] = s2; sqpart[cbase * SQP + px4 + 3] = s3;
        if (t < P) lab_s[t] = labv;
    }
    __syncthreads();

    for (int it = 0; it < TILES; ++it) {
        // A: prefetch next tile's globals (stay in flight across bar_lds)
        if (it + 1 < TILES) {
            const int p0 = (blockIdx.x + (it + 1) * GRID) * P;
            const int b = p0 >> 15, hw0 = p0 & (HW - 1);
            const float* fb = feats + (size_t)b * NCH * HW + hw0;
            #pragma unroll
            for (int i = 0; i < 8; ++i)
                v4[i] = *reinterpret_cast<const float4*>(fb + (size_t)(cbase + 32 * i) * HW + px4);
            if (t < P) labv = labels[p0 + t];
        }
        // B: one-hot MFMA; wave (ks,cg) owns K-pixels ks*32..+31, channels cg*64..+63.
        //    A/B share the k-mapping (h*8+j) -> any HW k-permutation cancels.
        #pragma unroll
        for (int kk = 0; kk < 2; ++kk) {
            const int pb = ks * 32 + kk * 16 + h * 8;
            const int4v lq0 = *reinterpret_cast<const int4v*>(&lab_s[pb]);
            const int4v lq1 = *reinterpret_cast<const int4v*>(&lab_s[pb + 4]);
            bf16x8v af;
            af[0] = (lq0[0] == col) ? ONE : ZER;  af[1] = (lq0[1] == col) ? ONE : ZER;
            af[2] = (lq0[2] == col) ? ONE : ZER;  af[3] = (lq0[3] == col) ? ONE : ZER;
            af[4] = (lq1[0] == col) ? ONE : ZER;  af[5] = (lq1[1] == col) ? ONE : ZER;
            af[6] = (lq1[2] == col) ? ONE : ZER;  af[7] = (lq1[3] == col) ? ONE : ZER;
            const bf16x4v b0l = *reinterpret_cast<const bf16x4v*>(&tileh[c0 * THP + pb]);
            const bf16x4v b0h = *reinterpret_cast<const bf16x4v*>(&tileh[c0 * THP + pb + 4]);
            const bf16x4v b1l = *reinterpret_cast<const bf16x4v*>(&tileh[c1 * THP + pb]);
            const bf16x4v b1h = *reinterpret_cast<const bf16x4v*>(&tileh[c1 * THP + pb + 4]);
            const bf16x8v bf0 = __builtin_shufflevector(b0l, b0h, 0,1,2,3,4,5,6,7);
            const bf16x8v bf1 = __builtin_shufflevector(b1l, b1h, 0,1,2,3,4,5,6,7);
            d0 = __builtin_amdgcn_mfma_f32_32x32x16_bf16(af, bf0, d0, 0, 0, 0);
            d1 = __builtin_amdgcn_mfma_f32_32x32x16_bf16(af, bf1, d1, 0, 0, 0);
        }
        if (t < P) {   // finish norms for current tile (wave 0; 2-way banks = free)
            float s = 0.f;
            #pragma unroll
            for (int m = 0; m < 32; ++m) s += sqpart[m * SQP + t];
            const int k = lab_s[t];
            unsafeAtomicAdd(&accN[k], sqrtf(s));
            unsafeAtomicAdd(&accC[k], 1.f);
        }
        bar_lds();   // tile reads retired; prefetch loads NOT drained
        // D: stage prefetched tile (cvt/ds_write wait on own v4 regs only)
        if (it + 1 < TILES) {
            float s0 = 0.f, s1 = 0.f, s2 = 0.f, s3 = 0.f;
            #pragma unroll
            for (int i = 0; i < 8; ++i) {
                const int c = cbase + 32 * i;
                bf16x4v hv = { (__bf16)v4[i].x, (__bf16)v4[i].y, (__bf16)v4[i].z, (__bf16)v4[i].w };
                *reinterpret_cast<bf16x4v*>(&tileh[c * THP + px4]) = hv;
                s0 += v4[i].x * v4[i].x; s1 += v4[i].y * v4[i].y;
                s2 += v4[i].z * v4[i].z; s3 += v4[i].w * v4[i].w;
            }
            sqpart[cbase * SQP + px4    ] = s0; sqpart[cbase * SQP + px4 + 1] = s1;
            sqpart[cbase * SQP + px4 + 2] = s2; sqpart[cbase * SQP + px4 + 3] = s3;
            if (t < P) lab_s[t] = labv;
        }
        bar_lds();
    }

    // ---- merge K-halves (native ds_add_f32; 2 waves collide per slot), flush ----
    __syncthreads();
    #pragma unroll
    for (int r = 0; r < 16; ++r) {
        const int row = (r & 3) + 8 * (r >> 2) + 4 * h;   // C/D row = class
        if (row < NCLS) {
            unsafeAtomicAdd(&accf[row * NCH + c0], d0[r]);
            unsafeAtomicAdd(&accf[row * NCH + c1], d1[r]);
        }
    }
    __syncthreads();
    float* op = partials + (size_t)blockIdx.x * PSTRIDE;
    for (int j = t; j < SUMS; j += 512) op[j] = accf[j];   // coalesced
    if (t < NCLS) { op[PN_NORM + t] = accN[t]; op[PN_CNT + t] = accC[t]; }
}

// Fused reduce (r9 verbatim): 16 output slots/block over 512 group-partials;
// redundant 19-count reduce (19 x 8 lanes); divide.
__global__ __launch_bounds__(256) void reduce_kernel(
    const float* __restrict__ partials, float* __restrict__ out)
{
    __shared__ float cred[NCLS][9];
    __shared__ float red[16][17];
    __shared__ float cnt_s[NCLS];
    const int t = threadIdx.x;

    if (t < NCLS * 8) {
        const int k = t >> 3, gl = t & 7;
        float c = 0.f;
        #pragma unroll 8
        for (int j = 0; j < GRID / 8; ++j)
            c += partials[(size_t)(gl + 8 * j) * PSTRIDE + PN_CNT + k];
        cred[k][gl] = c;
    }
    {
        const int ol = t & 15, gl = t >> 4;
        const int o = blockIdx.x * 16 + ol;
        float s = 0.f;
        if (o < PN_CNT) {
            #pragma unroll 8
            for (int j = 0; j < GRID / 16; ++j)
                s += partials[(size_t)(gl + 16 * j) * PSTRIDE + o];
        }
        red[gl][ol] = s;
    }
    __syncthreads();
    if (t < NCLS) {
        float c = 0.f;
        #pragma unroll
        for (int g = 0; g < 8; ++g) c += cred[t][g];
        cnt_s[t] = c;
    }
    __syncthreads();
    if (t < 16) {
        const int oo = blockIdx.x * 16 + t;
        if (oo < PN_CNT) {
            float tot = 0.f;
            #pragma unroll
            for (int g = 0; g < 16; ++g) tot += red[g][t];
            const int k = (oo < SUMS) ? (oo >> 8) : (oo - SUMS);
            const float c = cnt_s[k];
            out[oo] = (c > 0.f) ? tot / fmaxf(c, 1.f) : 0.f;
        }
    }
}

extern "C" void kernel_launch(void* const* d_in, const int* in_sizes, int n_in,
                              void* d_out, int out_size, void* d_ws, size_t ws_size,
                              hipStream_t stream) {
    const float* feats  = (const float*)d_in[0];
    const int*   labels = (const int*)d_in[1];
    float* out      = (float*)d_out;
    float* partials = (float*)d_ws;            // 512*4928*4 = 10.1 MB

    accum_kernel<<<GRID, 512, 0, stream>>>(feats, labels, partials);
    reduce_kernel<<<(PN_CNT + 15) / 16, 256, 0, stream>>>(partials, out);
}

// Round 12
// 59.776 us; speedup vs baseline: 1.3427x; 1.3427x over previous
//
#include <hip/hip_runtime.h>

// feats [B=8, C=256, H=128, W=256] f32; labels [8,128,256] int32 in [0,19)
// out: means [19][256] then norm_means [19]  (4883 floats)
#define NCLS 19
#define NCH  256
#define HW   (128 * 256)         // 32768, pow2
#define NPIX (8 * HW)            // 262144
#define P    64                  // pixels per tile (256-B global segments/channel)
#define THP  68                  // bf16 tile row stride: 136 B, 8B-aligned b64, 2-way banks
#define SQG  16                  // sq-partial groups (16 channels each)
#define SQP  65                  // sqpart row stride
#define SUMS (NCLS * NCH)        // 4864
#define PN_NORM SUMS
#define PN_CNT  (SUMS + NCLS)
#define PSTRIDE 4928             // per-block partial stride (floats)
#define GRID  512
#define TILES (NPIX / (P * GRID))   // 8

typedef __bf16 bf16x4v __attribute__((ext_vector_type(4)));
typedef __bf16 bf16x8v __attribute__((ext_vector_type(8)));
typedef float  f32x16v __attribute__((ext_vector_type(16)));
typedef int    int4v   __attribute__((ext_vector_type(4)));

// LDS-only barrier (no vmcnt drain): prefetch loads stay in flight.
__device__ __forceinline__ void bar_lds() {
    asm volatile("s_waitcnt lgkmcnt(0)" ::: "memory");
    __builtin_amdgcn_sched_barrier(0);
    __builtin_amdgcn_s_barrier();
    __builtin_amdgcn_sched_barrier(0);
}

__global__ __launch_bounds__(256) void accum_kernel(
    const float* __restrict__ feats, const int* __restrict__ labels,
    float* __restrict__ partials)
{
    __shared__ __bf16 tileh[NCH * THP];   // 34.8 KB  [c][px] bf16
    __shared__ float  sqpart[SQG * SQP];  // 4.2 KB   [grp][px] x^2 partial (16 ch/grp)
    __shared__ float  accN[NCLS];
    __shared__ float  accC[NCLS];
    __shared__ int    lab_s[P];           // ~39.4 KB total

    const int t = threadIdx.x;
    if (t < NCLS) { accN[t] = 0.f; accC[t] = 0.f; }

    // Stage mapping: thread covers 16 channels x 4 px.
    // Wave-load = 4 channels x 64 px = 4 x 256-B contiguous segments.
    const int px4 = (t & 15) * 4, cbase = t >> 4;
    const int w = t >> 6, l = t & 63, h = l >> 5, col = l & 31;
    const int c0 = w * 64 + col, c1 = c0 + 32;    // lane's two output channels
    const __bf16 ONE = (__bf16)1.0f, ZER = (__bf16)0.0f;

    f32x16v d0 = {}, d1 = {};                     // class x channel accumulators
    float4 v4[16];
    int labv = 0;

    // ---- prologue: load + stage tile 0 ----
    {
        const int p0 = blockIdx.x * P, b = p0 >> 15, hw0 = p0 & (HW - 1);
        const float* fb = feats + (size_t)b * NCH * HW + hw0;
        #pragma unroll
        for (int i = 0; i < 16; ++i)
            v4[i] = *reinterpret_cast<const float4*>(fb + (size_t)(cbase + 16 * i) * HW + px4);
        if (t < P) labv = labels[p0 + t];
    }
    {
        float s0 = 0.f, s1 = 0.f, s2 = 0.f, s3 = 0.f;
        #pragma unroll
        for (int i = 0; i < 16; ++i) {
            const int c = cbase + 16 * i;
            bf16x4v hv = { (__bf16)v4[i].x, (__bf16)v4[i].y, (__bf16)v4[i].z, (__bf16)v4[i].w };
            *reinterpret_cast<bf16x4v*>(&tileh[c * THP + px4]) = hv;
            s0 += v4[i].x * v4[i].x; s1 += v4[i].y * v4[i].y;
            s2 += v4[i].z * v4[i].z; s3 += v4[i].w * v4[i].w;
        }
        sqpart[cbase * SQP + px4    ] = s0; sqpart[cbase * SQP + px4 + 1] = s1;
        sqpart[cbase * SQP + px4 + 2] = s2; sqpart[cbase * SQP + px4 + 3] = s3;
        if (t < P) lab_s[t] = labv;
    }
    __syncthreads();

    for (int it = 0; it < TILES; ++it) {
        // A: prefetch next tile's globals (stay in flight across bar_lds)
        if (it + 1 < TILES) {
            const int p0 = (blockIdx.x + (it + 1) * GRID) * P;
            const int b = p0 >> 15, hw0 = p0 & (HW - 1);
            const float* fb = feats + (size_t)b * NCH * HW + hw0;
            #pragma unroll
            for (int i = 0; i < 16; ++i)
                v4[i] = *reinterpret_cast<const float4*>(fb + (size_t)(cbase + 16 * i) * HW + px4);
            if (t < P) labv = labels[p0 + t];
        }
        // B: one-hot MFMA segment-sum over 4 K-steps (pixels = K axis).
        //    A/B share the k-mapping (h*8+j) -> any HW k-permutation cancels.
        #pragma unroll
        for (int kk = 0; kk < 4; ++kk) {
            const int pb = kk * 16 + h * 8;
            const int4v lq0 = *reinterpret_cast<const int4v*>(&lab_s[pb]);
            const int4v lq1 = *reinterpret_cast<const int4v*>(&lab_s[pb + 4]);
            bf16x8v af;
            af[0] = (lq0[0] == col) ? ONE : ZER;  af[1] = (lq0[1] == col) ? ONE : ZER;
            af[2] = (lq0[2] == col) ? ONE : ZER;  af[3] = (lq0[3] == col) ? ONE : ZER;
            af[4] = (lq1[0] == col) ? ONE : ZER;  af[5] = (lq1[1] == col) ? ONE : ZER;
            af[6] = (lq1[2] == col) ? ONE : ZER;  af[7] = (lq1[3] == col) ? ONE : ZER;
            const bf16x4v b0l = *reinterpret_cast<const bf16x4v*>(&tileh[c0 * THP + pb]);
            const bf16x4v b0h = *reinterpret_cast<const bf16x4v*>(&tileh[c0 * THP + pb + 4]);
            const bf16x4v b1l = *reinterpret_cast<const bf16x4v*>(&tileh[c1 * THP + pb]);
            const bf16x4v b1h = *reinterpret_cast<const bf16x4v*>(&tileh[c1 * THP + pb + 4]);
            const bf16x8v bf0 = __builtin_shufflevector(b0l, b0h, 0,1,2,3,4,5,6,7);
            const bf16x8v bf1 = __builtin_shufflevector(b1l, b1h, 0,1,2,3,4,5,6,7);
            d0 = __builtin_amdgcn_mfma_f32_32x32x16_bf16(af, bf0, d0, 0, 0, 0);
            d1 = __builtin_amdgcn_mfma_f32_32x32x16_bf16(af, bf1, d1, 0, 0, 0);
        }
        if (t < P) {   // finish norms for current tile (f32 path, wave 0)
            float s = 0.f;
            #pragma unroll
            for (int g = 0; g < SQG; ++g) s += sqpart[g * SQP + t];  // 2-way banks
            const int k = lab_s[t];
            unsafeAtomicAdd(&accN[k], sqrtf(s));
            unsafeAtomicAdd(&accC[k], 1.f);
        }
        bar_lds();   // tile reads retired; prefetch loads NOT drained
        // D: stage prefetched tile (cvt/ds_write wait on own v4 regs only)
        if (it + 1 < TILES) {
            float s0 = 0.f, s1 = 0.f, s2 = 0.f, s3 = 0.f;
            #pragma unroll
            for (int i = 0; i < 16; ++i) {
                const int c = cbase + 16 * i;
                bf16x4v hv = { (__bf16)v4[i].x, (__bf16)v4[i].y, (__bf16)v4[i].z, (__bf16)v4[i].w };
                *reinterpret_cast<bf16x4v*>(&tileh[c * THP + px4]) = hv;
                s0 += v4[i].x * v4[i].x; s1 += v4[i].y * v4[i].y;
                s2 += v4[i].z * v4[i].z; s3 += v4[i].w * v4[i].w;
            }
            sqpart[cbase * SQP + px4    ] = s0; sqpart[cbase * SQP + px4 + 1] = s1;
            sqpart[cbase * SQP + px4 + 2] = s2; sqpart[cbase * SQP + px4 + 3] = s3;
            if (t < P) lab_s[t] = labv;
        }
        bar_lds();
    }

    // ---- flush: accumulators -> partials (C/D layout: col=lane&31,
    //      row=(reg&3)+8*(reg>>2)+4*(lane>>5)), rows 19..31 discarded ----
    float* op = partials + (size_t)blockIdx.x * PSTRIDE;
    #pragma unroll
    for (int r = 0; r < 16; ++r) {
        const int k = (r & 3) + 8 * (r >> 2) + 4 * h;
        if (k < NCLS) {
            op[k * NCH + c0] = d0[r];
            op[k * NCH + c1] = d1[r];
        }
    }
    if (t < NCLS) { op[PN_NORM + t] = accN[t]; op[PN_CNT + t] = accC[t]; }
}

// Fused reduce: each block reduces 16 output slots over 512 group-partials,
// redundantly reduces the 19 counts (19 classes x 8 lanes), divides.
__global__ __launch_bounds__(256) void reduce_kernel(
    const float* __restrict__ partials, float* __restrict__ out)
{
    __shared__ float cred[NCLS][9];
    __shared__ float red[16][17];
    __shared__ float cnt_s[NCLS];
    const int t = threadIdx.x;

    if (t < NCLS * 8) {
        const int k = t >> 3, gl = t & 7;
        float c = 0.f;
        #pragma unroll 8
        for (int j = 0; j < GRID / 8; ++j)
            c += partials[(size_t)(gl + 8 * j) * PSTRIDE + PN_CNT + k];
        cred[k][gl] = c;
    }
    {
        const int ol = t & 15, gl = t >> 4;
        const int o = blockIdx.x * 16 + ol;
        float s = 0.f;
        if (o < PN_CNT) {
            #pragma unroll 8
            for (int j = 0; j < GRID / 16; ++j)
                s += partials[(size_t)(gl + 16 * j) * PSTRIDE + o];
        }
        red[gl][ol] = s;
    }
    __syncthreads();
    if (t < NCLS) {
        float c = 0.f;
        #pragma unroll
        for (int g = 0; g < 8; ++g) c += cred[t][g];
        cnt_s[t] = c;
    }
    __syncthreads();
    if (t < 16) {
        const int oo = blockIdx.x * 16 + t;
        if (oo < PN_CNT) {
            float tot = 0.f;
            #pragma unroll
            for (int g = 0; g < 16; ++g) tot += red[g][t];
            const int k = (oo < SUMS) ? (oo >> 8) : (oo - SUMS);
            const float c = cnt_s[k];
            out[oo] = (c > 0.f) ? tot / fmaxf(c, 1.f) : 0.f;
        }
    }
}

extern "C" void kernel_launch(void* const* d_in, const int* in_sizes, int n_in,
                              void* d_out, int out_size, void* d_ws, size_t ws_size,
                              hipStream_t stream) {
    const float* feats  = (const float*)d_in[0];
    const int*   labels = (const int*)d_in[1];
    float* out      = (float*)d_out;
    float* partials = (float*)d_ws;            // 512*4928*4 = 10.1 MB

    accum_kernel<<<GRID, 256, 0, stream>>>(feats, labels, partials);
    reduce_kernel<<<(PN_CNT + 15) / 16, 256, 0, stream>>>(partials, out);
}